// Round 1
// baseline (134.530 us; speedup 1.0000x reference)
//
#include <hip/hip_runtime.h>
#include <hip/hip_bf16.h>
#include <math.h>

// Problem constants: B=1024 batch, L=256 latent, H=512 hidden, T=16 types,
// N=128 nodes (num_nodes input is a fixed scalar = 128).
#define BB 1024
#define LL 256
#define HH 512
#define TT 16
#define NN 128

#define NODE_F4 (BB * NN * TT / 4)   // 524288 float4
#define EDGE_F4 (BB * NN * NN / 4)   // 4194304 float4

typedef short bf16x8 __attribute__((ext_vector_type(8)));   // 8 bf16 = 4 VGPRs
typedef float f32x4  __attribute__((ext_vector_type(4)));   // MFMA C/D

static __device__ __forceinline__ short bfbits(float f) {
    __hip_bfloat16 h = __float2bfloat16(f);
    return *reinterpret_cast<short*>(&h);
}

// h LDS layout: 16 rows x 512 bf16 = 16 x 1024 B. XOR-swizzle the 16B chunk
// index with (row&7): the phase-2/3 A-frag reads (64 lanes, 16 distinct rows,
// 16B each at the same k-offset) would otherwise be an 8-way bank conflict
// (1024B row stride); swizzled they spread over all 8 bank groups -> 2-way
// (free, m136). Phase-1 stores are scalar b16 and don't care.
static __device__ __forceinline__ int h_addr(int row, int col) {
    return (row << 10) + ((((col >> 3) ^ (row & 7)) << 4)) + ((col & 7) << 1);
}

// ---------------------------------------------------------------------------
// K_PREP — weights-only prologue (z conversion + p_acc zero now fused away):
//   [0,128)   WzT[n][k]   = bf16(Wz[k][n])                (512x256, 32x32 tiles)
//   [128,384) WsumT[n][k] = bf16(We1[k][n]+We1[k+512][n]) (512x512 tiles)
//   [384,416) WnT[t][k]   = bf16(Wn[k][t])               (16x512, tiny)
__device__ __forceinline__ void transpose_tile(const float* __restrict__ in,
                                               __hip_bfloat16* __restrict__ out,
                                               int k0, int n0, int Kdim, bool fold,
                                               __hip_bfloat16 (*tile)[34]) {
    const int tx = threadIdx.x & 31;
    const int ty = threadIdx.x >> 5;          // 0..7
    #pragma unroll
    for (int r = ty; r < 32; r += 8) {
        float v = in[(k0 + r) * HH + n0 + tx];        // row stride is 512 both uses
        if (fold) v += in[(k0 + r + HH) * HH + n0 + tx];
        tile[r][tx] = __float2bfloat16(v);
    }
    __syncthreads();
    #pragma unroll
    for (int r = ty; r < 32; r += 8) {
        out[(n0 + r) * Kdim + k0 + tx] = tile[tx][r];
    }
}

__global__ __launch_bounds__(256) void k_prep(const float* __restrict__ Wz,
                                              const float* __restrict__ We1,
                                              const float* __restrict__ Wn,
                                              __hip_bfloat16* __restrict__ WzT,
                                              __hip_bfloat16* __restrict__ WsumT,
                                              __hip_bfloat16* __restrict__ WnT) {
    __shared__ __hip_bfloat16 tile[32][34];   // +2 pad: conflict-free col reads
    const int bid = blockIdx.x;
    const int tid = threadIdx.x;
    if (bid < 128) {                          // 8 k-tiles x 16 n-tiles
        transpose_tile(Wz, WzT, (bid >> 4) * 32, (bid & 15) * 32, LL, false, tile);
    } else if (bid < 384) {                   // 16 k-tiles x 16 n-tiles
        const int t = bid - 128;
        transpose_tile(We1, WsumT, (t >> 4) * 32, (t & 15) * 32, HH, true, tile);
    } else {
        const int u = (bid - 384) * 256 + tid;   // 0..8191
        const int tt = u >> 9, k = u & 511;
        WnT[u] = __float2bfloat16(Wn[k * TT + tt]);
    }
}

// ---------------------------------------------------------------------------
// K_FUSED — one block per 16 batch rows (64 blocks x 8 waves). Rows are
// independent through every head, so the whole chain after the weight
// transposes lives in one kernel with zero cross-block traffic:
//   phase 1: h[16x512] = relu(z @ Wz + bz) -> bf16 in LDS (z converted
//            in-register from fp32; no z_bf / h_bf globals).
//   phase 2: node16 partial = h @ WnT^T, K split 8 ways across waves.
//   phase 3: p-head: per 16x16 tile of relu(h @ Wsum + be1) * We2[col],
//            shfl_xor butterfly over the 16 col-lanes, per-wave partials
//            to LDS (no atomics), finalize sigmoid per row.
__global__ __launch_bounds__(512) void k_fused(const float* __restrict__ z,
                                               const __hip_bfloat16* __restrict__ WzT,
                                               const __hip_bfloat16* __restrict__ WsumT,
                                               const __hip_bfloat16* __restrict__ WnT,
                                               const float* __restrict__ bz,
                                               const float* __restrict__ be1,
                                               const float* __restrict__ We2,
                                               const float* __restrict__ bn,
                                               const float* __restrict__ be2,
                                               float* __restrict__ node16,
                                               float* __restrict__ p) {
    __shared__ char  hbuf[16384];        // h, swizzled (see h_addr)
    __shared__ f32x4 nod_lds[8][64];     // node16 K-partials, 8 KB
    __shared__ float pw_lds[8][16];      // p-head wave partials

    const int w    = threadIdx.x >> 6;   // wave 0..7
    const int lane = threadIdx.x & 63;
    const int l16  = lane & 15, quad = lane >> 4;
    const int r0   = blockIdx.x << 4;    // this block's batch rows

    // ---- phase 1: h = relu(z @ Wz + bz), A-frags straight from fp32 z ----
    bf16x8 afr[8];
    {
        const float4* zf = (const float4*)(z + (r0 + l16) * LL);
        #pragma unroll
        for (int kt = 0; kt < 8; ++kt) {
            float4 v0 = zf[quad * 2 + kt * 8];
            float4 v1 = zf[quad * 2 + kt * 8 + 1];
            bf16x8 a;
            a[0] = bfbits(v0.x); a[1] = bfbits(v0.y); a[2] = bfbits(v0.z); a[3] = bfbits(v0.w);
            a[4] = bfbits(v1.x); a[5] = bfbits(v1.y); a[6] = bfbits(v1.z); a[7] = bfbits(v1.w);
            afr[kt] = a;
        }
    }
    #pragma unroll
    for (int i = 0; i < 4; ++i) {        // wave w owns h cols [w*64, w*64+64)
        const int nt = (w << 2) + i;
        const short* Bp = (const short*)WzT + (nt * 16 + l16) * LL + quad * 8;
        f32x4 acc = {0.f, 0.f, 0.f, 0.f};
        #pragma unroll
        for (int kt = 0; kt < 8; ++kt) {
            bf16x8 b = *(const bf16x8*)(Bp + kt * 32);
            acc = __builtin_amdgcn_mfma_f32_16x16x32_bf16(afr[kt], b, acc, 0, 0, 0);
        }
        const int col = nt * 16 + l16;
        const float bb = bz[col];
        #pragma unroll
        for (int r = 0; r < 4; ++r) {    // C/D: row=quad*4+r, col=l16 (m89)
            float hv = fmaxf(acc[r] + bb, 0.f);
            *(short*)(hbuf + h_addr(quad * 4 + r, col)) = bfbits(hv);
        }
    }
    __syncthreads();

    // ---- phase 2: node16 partial, wave w covers kt = 2w, 2w+1 (K=512) ----
    {
        f32x4 acc = {0.f, 0.f, 0.f, 0.f};
        const short* Bp = (const short*)WnT + l16 * HH + quad * 8;
        #pragma unroll
        for (int kk = 0; kk < 2; ++kk) {
            const int kt = w * 2 + kk;
            bf16x8 a = *(const bf16x8*)(hbuf + h_addr(l16, quad * 8 + kt * 32));
            bf16x8 b = *(const bf16x8*)(Bp + kt * 32);
            acc = __builtin_amdgcn_mfma_f32_16x16x32_bf16(a, b, acc, 0, 0, 0);
        }
        nod_lds[w][lane] = acc;
    }

    // ---- phase 3: p-head, wave w covers e1 cols [w*64, w*64+64) ----
    {
        f32x4 acc[4];
        #pragma unroll
        for (int i = 0; i < 4; ++i) acc[i] = (f32x4){0.f, 0.f, 0.f, 0.f};
        #pragma unroll
        for (int kt = 0; kt < 16; ++kt) {
            bf16x8 a = *(const bf16x8*)(hbuf + h_addr(l16, quad * 8 + kt * 32));
            #pragma unroll
            for (int i = 0; i < 4; ++i) {
                const int nt = (w << 2) + i;
                bf16x8 b = *(const bf16x8*)((const short*)WsumT +
                            (nt * 16 + l16) * HH + quad * 8 + kt * 32);
                acc[i] = __builtin_amdgcn_mfma_f32_16x16x32_bf16(a, b, acc[i], 0, 0, 0);
            }
        }
        float psum[4] = {0.f, 0.f, 0.f, 0.f};
        #pragma unroll
        for (int i = 0; i < 4; ++i) {
            const int col = ((w << 2) + i) * 16 + l16;
            const float bb = be1[col], w2 = We2[col];
            float sr[4];
            #pragma unroll
            for (int r = 0; r < 4; ++r) sr[r] = fmaxf(acc[i][r] + bb, 0.f) * w2;
            #pragma unroll
            for (int off = 1; off < 16; off <<= 1) {   // sum over the 16 col-lanes
                #pragma unroll
                for (int r = 0; r < 4; ++r) sr[r] += __shfl_xor(sr[r], off);
            }
            #pragma unroll
            for (int r = 0; r < 4; ++r) psum[r] += sr[r];
        }
        if (l16 == 0) {
            #pragma unroll
            for (int r = 0; r < 4; ++r) pw_lds[w][quad * 4 + r] = psum[r];
        }
    }
    __syncthreads();

    // ---- finalize: wave 0 reduces node16, wave 1 reduces p ----
    if (w == 0) {
        f32x4 s = nod_lds[0][lane];
        #pragma unroll
        for (int ww = 1; ww < 8; ++ww) {
            f32x4 t = nod_lds[ww][lane];
            s[0] += t[0]; s[1] += t[1]; s[2] += t[2]; s[3] += t[3];
        }
        const float bb = bn[l16];
        #pragma unroll
        for (int r = 0; r < 4; ++r)
            node16[(r0 + quad * 4 + r) * TT + l16] = s[r] + bb;
    } else if (w == 1 && lane < 16) {
        float t = 0.f;
        #pragma unroll
        for (int ww = 0; ww < 8; ++ww) t += pw_lds[ww][lane];
        t += be2[0];
        p[r0 + lane] = 1.f / (1.f + expf(-t));
    }
}

// ---------------------------------------------------------------------------
// K_WRITE: the 72 MiB broadcast write (the true roofline term, ~13 us).
// out = [node_logits 1024x128x16][edge_probs 1024x128x128] fp32.
__global__ __launch_bounds__(256) void k_write(const float* __restrict__ node16,
                                               const float* __restrict__ p,
                                               float4* __restrict__ out) {
    const int q = blockIdx.x * 256 + threadIdx.x;
    if (q < NODE_F4) {
        const int b  = q >> 9;           // N*T/4 = 512 f4 per batch row
        const int t4 = q & 3;
        out[q] = ((const float4*)(node16 + b * TT))[t4];
    } else {
        const int e  = q - NODE_F4;
        const int b  = e >> 12;          // N*N/4 = 4096 f4 per batch row
        const int i  = (e >> 5) & 127;
        const int j0 = (e & 31) * 4;
        const float pv = p[b];
        float4 v;
        v.x = (j0 + 0 < i) ? pv : 0.f;
        v.y = (j0 + 1 < i) ? pv : 0.f;
        v.z = (j0 + 2 < i) ? pv : 0.f;
        v.w = (j0 + 3 < i) ? pv : 0.f;
        out[q] = v;
    }
}

// ---------------------------------------------------------------------------
extern "C" void kernel_launch(void* const* d_in, const int* in_sizes, int n_in,
                              void* d_out, int out_size, void* d_ws, size_t ws_size,
                              hipStream_t stream) {
    const float* z    = (const float*)d_in[0];
    // d_in[1] = num_nodes (int scalar) — fixed at 128, hard-coded as NN.
    const float* Wz   = (const float*)d_in[2];
    const float* bz   = (const float*)d_in[3];
    const float* Wn   = (const float*)d_in[4];
    const float* bn   = (const float*)d_in[5];
    const float* We1  = (const float*)d_in[6];
    const float* be1  = (const float*)d_in[7];
    const float* We2  = (const float*)d_in[8];
    const float* be2  = (const float*)d_in[9];
    float* out = (float*)d_out;

    // Workspace (bytes, 256B-aligned):
    char* base = (char*)d_ws;
    __hip_bfloat16* WzT    = (__hip_bfloat16*)(base);                 // 256 KB [512][256]
    __hip_bfloat16* WsumT  = (__hip_bfloat16*)(base +  256 * 1024);   // 512 KB [512][512]
    __hip_bfloat16* WnT    = (__hip_bfloat16*)(base +  768 * 1024);   //  16 KB [16][512]
    float*          node16 = (float*)(base + 784 * 1024);             //  64 KB [1024][16]
    float*          p      = (float*)(base + 848 * 1024);             //   4 KB

    // 1) weight transposes only
    k_prep<<<416, 256, 0, stream>>>(Wz, We1, Wn, WzT, WsumT, WnT);

    // 2) fully-fused per-16-rows compute: h (LDS-only) -> node16 + p
    k_fused<<<BB / 16, 512, 0, stream>>>(z, WzT, WsumT, WnT,
                                         bz, be1, We2, bn, be2, node16, p);

    // 3) 72 MiB broadcast write
    k_write<<<(NODE_F4 + EDGE_F4) / 256, 256, 0, stream>>>(node16, p, (float4*)out);

    (void)in_sizes; (void)n_in; (void)out_size; (void)ws_size;
}